// Round 2
// baseline (557.591 us; speedup 1.0000x reference)
//
#include <hip/hip_runtime.h>
#include <hip/hip_bf16.h>
#include <math.h>

using short8 = __attribute__((ext_vector_type(8))) short;
using f32x4  = __attribute__((ext_vector_type(4))) float;

static __device__ __forceinline__ f32x4 mfma16(short8 a, short8 b, f32x4 c){
    return __builtin_amdgcn_mfma_f32_16x16x32_bf16(a, b, c, 0, 0, 0);
}

// round-to-nearest-even f32 -> bf16 bits (finite values only)
static __device__ __forceinline__ unsigned short bf16of(float f){
    unsigned int u = __float_as_uint(f);
    unsigned int lsb = (u >> 16) & 1u;
    u += 0x7fffu + lsb;
    return (unsigned short)(u >> 16);
}

// ---------------------------------------------------------------- prep
__global__ void prep_weights(const float* __restrict__ w1, const float* __restrict__ w2,
                             unsigned short* __restrict__ w1b, unsigned short* __restrict__ w2b){
    int i = blockIdx.x * 256 + threadIdx.x;
    if (i < 4*256*256){
        w1b[i] = bf16of(w1[i]);
        w2b[i] = bf16of(w2[i]);
    }
}

// ---------------------------------------------------------------- conv + LN
#define CH 16          // output h-rows per block
#define XR (CH + 6)    // input rows incl. halo
#define XW 262         // tile width incl. halo

__global__ __launch_bounds__(256) void conv_ln_kernel(
    const float* __restrict__ x, const float* __restrict__ conv_w,
    const float* __restrict__ conv_b, const float* __restrict__ ln_g,
    const float* __restrict__ ln_b, unsigned short* __restrict__ ynorm)
{
    __shared__ float xt[XR * XW];
    __shared__ float yt[CH * 256];

    const int tid = threadIdx.x;
    const int blk = blockIdx.x;
    const int ht = blk & 15;
    const int c  = (blk >> 4) & 255;
    const int b  = blk >> 12;
    const int h0 = ht * CH;

    const float* xplane = x + (((size_t)(b*256 + c)) << 16);

    // stage x tile (zero-padded halo)
    for (int i = tid; i < XR*XW; i += 256){
        int r = i / XW;
        int col = i - r*XW;
        int gh = h0 - 3 + r;
        int gw = col - 3;
        float v = 0.f;
        if ((unsigned)gh < 256u && (unsigned)gw < 256u)
            v = xplane[gh*256 + gw];
        xt[i] = v;
    }

    // conv weights: uniform address -> scalar loads
    float cwr[49];
    #pragma unroll
    for (int i = 0; i < 49; ++i) cwr[i] = conv_w[c*49 + i];
    const float cb = conv_b[c];

    __syncthreads();

    // one thread per w column, sliding-row accumulation over CH output rows
    const int w = tid;
    float acc[CH];
    #pragma unroll
    for (int r = 0; r < CH; ++r) acc[r] = 0.f;

    #pragma unroll
    for (int i = 0; i < XR; ++i){
        #pragma unroll
        for (int j = 0; j < 7; ++j){
            float v = xt[i*XW + w + j];
            #pragma unroll
            for (int ro = 0; ro < CH; ++ro){
                if (ro >= i - 6 && ro <= i)      // constant-folds after unroll
                    acc[ro] = fmaf(v, cwr[(i - ro)*7 + j], acc[ro]);
            }
        }
    }

    #pragma unroll
    for (int r = 0; r < CH; ++r) yt[r*256 + w] = acc[r] + cb;

    __syncthreads();

    // LayerNorm over w: one wave per row
    const int lane = tid & 63;
    const int wid  = tid >> 6;
    float lg[4], lb[4];
    #pragma unroll
    for (int q = 0; q < 4; ++q){ lg[q] = ln_g[lane + 64*q]; lb[q] = ln_b[lane + 64*q]; }

    for (int rr = 0; rr < CH/4; ++rr){
        int row = wid*(CH/4) + rr;
        float v[4], s = 0.f, ss = 0.f;
        #pragma unroll
        for (int q = 0; q < 4; ++q){
            v[q] = yt[row*256 + lane + 64*q];
            s += v[q]; ss += v[q]*v[q];
        }
        #pragma unroll
        for (int off = 32; off > 0; off >>= 1){
            s  += __shfl_xor(s, off);
            ss += __shfl_xor(ss, off);
        }
        float mu  = s * (1.f/256.f);
        float var = ss * (1.f/256.f) - mu*mu;
        float rs  = rsqrtf(var + 1e-5f);
        size_t M = (size_t)((b*256 + c)*256 + h0 + row);
        unsigned short* dst = ynorm + M*256;
        #pragma unroll
        for (int q = 0; q < 4; ++q){
            float o = (v[q] - mu)*rs*lg[q] + lb[q];
            dst[lane + 64*q] = bf16of(o);
        }
    }
}

// ---------------------------------------------------------------- fused MLP + transpose + residual
// 256 thr = 4 waves, M-tile 64. Waves split N. N-chunks of 128 (oc=0..7).
// LDS 48KB: Ash 64x256 bf16 (32KB, XOR-swizzled), Hsh 64x128 bf16 (16KB, swizzled).
// Epilogue: 4 rounds of 64w x 64h f32 transpose chunk aliased on Ash.
// GEMM2 N mapping interleaved (wcol = nfi*64 + wid*16 + l15) so every wave
// contributes nfi==round to each epilogue chunk.
__global__ __launch_bounds__(256, 3) void mlp_kernel(
    const unsigned short* __restrict__ ynorm,
    const short* __restrict__ w1b, const short* __restrict__ w2b,
    const float* __restrict__ b1, const float* __restrict__ b2,
    const float* __restrict__ x, float* __restrict__ out)
{
    __shared__ __align__(16) char smem[49152];
    short* Ash = (short*)smem;               // [64][256] bf16 swizzled
    short* Hsh = (short*)(smem + 32768);     // [64][128] bf16 swizzled
    float* OT  = (float*)smem;               // [64][64] f32 swizzled (aliases Ash)

    const int tid  = threadIdx.x;
    const int lane = tid & 63;
    const int wid  = tid >> 6;
    const int M0 = blockIdx.x * 64;
    const int b = M0 >> 16, c = (M0 >> 8) & 255, h0 = M0 & 255;

    const int l15  = lane & 15;
    const int kg   = lane >> 4;   // 0..3
    const int koff = kg * 8;

    // stage A tile (64 x 256 bf16), swizzle col8 ^= (row&7)
    {
        const uint4* src = reinterpret_cast<const uint4*>(ynorm + (size_t)M0*256);
        for (int i = tid; i < 2048; i += 256){
            int row = i >> 5, g = i & 31;
            uint4 v = src[i];
            *reinterpret_cast<uint4*>(Ash + row*256 + ((g ^ (row & 7)) << 3)) = v;
        }
    }
    __syncthreads();

    f32x4 acc2[4][4] = {};

    for (int oc = 0; oc < 8; ++oc){
        f32x4 acc1[4][2] = {};
        #pragma unroll
        for (int ks = 0; ks < 8; ++ks){
            short8 afr[4], bfr[2];
            #pragma unroll
            for (int mf = 0; mf < 4; ++mf){
                int row = mf*16 + l15;
                afr[mf] = *reinterpret_cast<const short8*>(
                    Ash + row*256 + (((ks*4 + kg) ^ (l15 & 7)) << 3));
            }
            #pragma unroll
            for (int nfl = 0; nfl < 2; ++nfl){
                int o = oc*128 + wid*32 + nfl*16 + l15;
                bfr[nfl] = *reinterpret_cast<const short8*>(w1b + o*256 + ks*32 + koff);
            }
            #pragma unroll
            for (int mf = 0; mf < 4; ++mf){
                #pragma unroll
                for (int nfl = 0; nfl < 2; ++nfl)
                    acc1[mf][nfl] = mfma16(afr[mf], bfr[nfl], acc1[mf][nfl]);
            }
        }
        __syncthreads();   // prev chunk's Hsh reads complete
        // bias + exact GELU -> Hsh (bf16, swizzled)
        #pragma unroll
        for (int nfl = 0; nfl < 2; ++nfl){
            int col = wid*32 + nfl*16 + l15;
            float bb = b1[oc*128 + col];
            #pragma unroll
            for (int mf = 0; mf < 4; ++mf){
                #pragma unroll
                for (int r = 0; r < 4; ++r){
                    int row = mf*16 + kg*4 + r;
                    float v = acc1[mf][nfl][r] + bb;
                    float g = 0.5f * v * (1.f + erff(v * 0.70710678118654752f));
                    Hsh[row*128 + (((col >> 3) ^ (row & 7)) << 3) + (col & 7)] = (short)bf16of(g);
                }
            }
        }
        __syncthreads();
        // GEMM2 partial over this K-chunk of 128
        #pragma unroll
        for (int ks = 0; ks < 4; ++ks){
            short8 hfr[4], bfr[4];
            #pragma unroll
            for (int mf = 0; mf < 4; ++mf){
                int row = mf*16 + l15;
                hfr[mf] = *reinterpret_cast<const short8*>(
                    Hsh + row*128 + (((ks*4 + kg) ^ (l15 & 7)) << 3));
            }
            #pragma unroll
            for (int nfi = 0; nfi < 4; ++nfi){
                int wcol = nfi*64 + wid*16 + l15;
                bfr[nfi] = *reinterpret_cast<const short8*>(w2b + wcol*1024 + oc*128 + ks*32 + koff);
            }
            #pragma unroll
            for (int mf = 0; mf < 4; ++mf){
                #pragma unroll
                for (int nfi = 0; nfi < 4; ++nfi)
                    acc2[mf][nfi] = mfma16(hfr[mf], bfr[nfi], acc2[mf][nfi]);
            }
        }
    }

    // epilogue: 4 rounds; round r transposes w-range [r*64, r*64+64)
    #pragma unroll
    for (int r = 0; r < 4; ++r){
        __syncthreads();   // OT region free (Ash reads / prev round reads done)
        int wl = wid*16 + l15;
        #pragma unroll
        for (int mf = 0; mf < 4; ++mf){
            #pragma unroll
            for (int j = 0; j < 4; ++j){
                int h = mf*16 + kg*4 + j;
                OT[wl*64 + (((h >> 2) ^ (wl & 15)) << 2) + (h & 3)] = acc2[mf][r][j];
            }
        }
        __syncthreads();
        #pragma unroll
        for (int it = 0; it < 4; ++it){
            int idx = it*256 + tid;
            int wl2 = idx >> 4, h4 = idx & 15;
            int wg = r*64 + wl2;
            float bb = b2[wg];
            size_t o = (((size_t)(b*256 + wg))*256 + (size_t)c)*256 + (size_t)(h0 + h4*4);
            float4 xa = *reinterpret_cast<const float4*>(x + o);
            int base = wl2*64 + ((h4 ^ (wl2 & 15)) << 2);
            float4 rv;
            rv.x = OT[base + 0] + bb + xa.x;
            rv.y = OT[base + 1] + bb + xa.y;
            rv.z = OT[base + 2] + bb + xa.z;
            rv.w = OT[base + 3] + bb + xa.w;
            *reinterpret_cast<float4*>(out + o) = rv;
        }
    }
}

// ---------------------------------------------------------------- launch
extern "C" void kernel_launch(void* const* d_in, const int* in_sizes, int n_in,
                              void* d_out, int out_size, void* d_ws, size_t ws_size,
                              hipStream_t stream)
{
    const float* x      = (const float*)d_in[0];
    const float* conv_w = (const float*)d_in[1];
    const float* conv_b = (const float*)d_in[2];
    const float* ln_g   = (const float*)d_in[3];
    const float* ln_b   = (const float*)d_in[4];
    const float* w1     = (const float*)d_in[5];
    const float* b1     = (const float*)d_in[6];
    const float* w2     = (const float*)d_in[7];
    const float* b2     = (const float*)d_in[8];
    float* out = (float*)d_out;

    unsigned short* ynorm = (unsigned short*)d_ws;                          // 67,108,864 B
    unsigned short* w1b   = (unsigned short*)((char*)d_ws + 67108864);      //    524,288 B
    unsigned short* w2b   = (unsigned short*)((char*)d_ws + 67108864 + 524288);

    hipLaunchKernelGGL(prep_weights, dim3(1024), dim3(256), 0, stream, w1, w2, w1b, w2b);
    hipLaunchKernelGGL(conv_ln_kernel, dim3(8192), dim3(256), 0, stream,
                       x, conv_w, conv_b, ln_g, ln_b, ynorm);
    hipLaunchKernelGGL(mlp_kernel, dim3(2048), dim3(256), 0, stream,
                       ynorm, (const short*)w1b, (const short*)w2b, b1, b2, x, out);
}

// Round 3
// 415.472 us; speedup vs baseline: 1.3421x; 1.3421x over previous
//
#include <hip/hip_runtime.h>
#include <hip/hip_bf16.h>
#include <math.h>

using short8 = __attribute__((ext_vector_type(8))) short;
using f32x4  = __attribute__((ext_vector_type(4))) float;

static __device__ __forceinline__ f32x4 mfma16(short8 a, short8 b, f32x4 c){
    return __builtin_amdgcn_mfma_f32_16x16x32_bf16(a, b, c, 0, 0, 0);
}

// round-to-nearest-even f32 -> bf16 bits (finite values only)
static __device__ __forceinline__ unsigned short bf16of(float f){
    unsigned int u = __float_as_uint(f);
    unsigned int lsb = (u >> 16) & 1u;
    u += 0x7fffu + lsb;
    return (unsigned short)(u >> 16);
}

// fast GELU (tanh form): max abs err ~3e-4, far under tolerance
static __device__ __forceinline__ float gelu_fast(float x){
    float x2 = x * x;
    float u2 = 1.5957691216057308f * x * fmaf(0.044715f, x2, 1.0f); // 2*sqrt(2/pi)*(x+0.044715x^3)
    float e  = __expf(-u2);
    return x * __builtin_amdgcn_rcpf(1.0f + e);
}

// ---------------------------------------------------------------- prep
// Pack w1/w2 into MFMA-fragment-major bf16 layouts:
// w1p[(n16*8 + ks)*64 + lane][8]: o = n16*16 + (lane&15), k = ks*32 + (lane>>4)*8 + j
// w2p[(n16*32 + ksg)*64 + lane][8]: n = n16*16 + (lane&15), k = ksg*32 + (lane>>4)*8 + j
__global__ __launch_bounds__(256) void prep_weights(
    const float* __restrict__ w1, const float* __restrict__ w2,
    unsigned short* __restrict__ w1p, unsigned short* __restrict__ w2p)
{
    int t = blockIdx.x * 256 + threadIdx.x;   // 0..65535
    int lane = t & 63;
    if (t < 32768){
        int g = t;
        int ks  = (g >> 6) & 7;
        int n16 = g >> 9;
        int o = n16*16 + (lane & 15);
        int k = ks*32 + (lane >> 4)*8;
        const float* src = w1 + o*256 + k;
        unsigned short* dst = w1p + (size_t)g*8;
        #pragma unroll
        for (int j = 0; j < 8; ++j) dst[j] = bf16of(src[j]);
    } else {
        int g = t - 32768;
        int ksg = (g >> 6) & 31;
        int n16 = g >> 11;
        int n = n16*16 + (lane & 15);
        int k = ksg*32 + (lane >> 4)*8;
        const float* src = w2 + n*1024 + k;
        unsigned short* dst = w2p + (size_t)g*8;
        #pragma unroll
        for (int j = 0; j < 8; ++j) dst[j] = bf16of(src[j]);
    }
}

// ---------------------------------------------------------------- conv + LN
#define CH 16          // output h-rows per block
#define XR (CH + 6)    // input rows incl. halo
#define XW 262         // tile width incl. halo

__global__ __launch_bounds__(256) void conv_ln_kernel(
    const float* __restrict__ x, const float* __restrict__ conv_w,
    const float* __restrict__ conv_b, const float* __restrict__ ln_g,
    const float* __restrict__ ln_b, unsigned short* __restrict__ ynorm)
{
    __shared__ float xt[XR * XW];
    __shared__ float yt[CH * 256];

    const int tid = threadIdx.x;
    const int blk = blockIdx.x;
    const int ht = blk & 15;
    const int c  = (blk >> 4) & 255;
    const int b  = blk >> 12;
    const int h0 = ht * CH;

    const float* xplane = x + (((size_t)(b*256 + c)) << 16);

    for (int i = tid; i < XR*XW; i += 256){
        int r = i / XW;
        int col = i - r*XW;
        int gh = h0 - 3 + r;
        int gw = col - 3;
        float v = 0.f;
        if ((unsigned)gh < 256u && (unsigned)gw < 256u)
            v = xplane[gh*256 + gw];
        xt[i] = v;
    }

    float cwr[49];
    #pragma unroll
    for (int i = 0; i < 49; ++i) cwr[i] = conv_w[c*49 + i];
    const float cb = conv_b[c];

    __syncthreads();

    const int w = tid;
    float acc[CH];
    #pragma unroll
    for (int r = 0; r < CH; ++r) acc[r] = 0.f;

    #pragma unroll
    for (int i = 0; i < XR; ++i){
        #pragma unroll
        for (int j = 0; j < 7; ++j){
            float v = xt[i*XW + w + j];
            #pragma unroll
            for (int ro = 0; ro < CH; ++ro){
                if (ro >= i - 6 && ro <= i)
                    acc[ro] = fmaf(v, cwr[(i - ro)*7 + j], acc[ro]);
            }
        }
    }

    #pragma unroll
    for (int r = 0; r < CH; ++r) yt[r*256 + w] = acc[r] + cb;

    __syncthreads();

    const int lane = tid & 63;
    const int wid  = tid >> 6;
    float lg[4], lb[4];
    #pragma unroll
    for (int q = 0; q < 4; ++q){ lg[q] = ln_g[lane + 64*q]; lb[q] = ln_b[lane + 64*q]; }

    for (int rr = 0; rr < CH/4; ++rr){
        int row = wid*(CH/4) + rr;
        float v[4], s = 0.f, ss = 0.f;
        #pragma unroll
        for (int q = 0; q < 4; ++q){
            v[q] = yt[row*256 + lane + 64*q];
            s += v[q]; ss += v[q]*v[q];
        }
        #pragma unroll
        for (int off = 32; off > 0; off >>= 1){
            s  += __shfl_xor(s, off);
            ss += __shfl_xor(ss, off);
        }
        float mu  = s * (1.f/256.f);
        float var = ss * (1.f/256.f) - mu*mu;
        float rs  = rsqrtf(var + 1e-5f);
        size_t M = (size_t)((b*256 + c)*256 + h0 + row);
        unsigned short* dst = ynorm + M*256;
        #pragma unroll
        for (int q = 0; q < 4; ++q){
            float o = (v[q] - mu)*rs*lg[q] + lb[q];
            dst[lane + 64*q] = bf16of(o);
        }
    }
}

// ---------------------------------------------------------------- fused MLP + transpose + residual
// 4 waves, M-tile 64, waves split N. N-chunk 256 (oc=0..3) -> 8 main barriers.
// LDS 64KB: Ash 64x256 bf16 swizzled (32KB), Hsh 64x256 bf16 swizzled (32KB).
// Packed fragment-major weights -> every B-frag load is one coalesced 1KB wave load.
// ks=0 fragments for the phase after the barriers are prefetched into registers
// before the barriers (compiler cannot hoist loads across __syncthreads).
__global__ __launch_bounds__(256, 2) void mlp_kernel(
    const unsigned short* __restrict__ ynorm,
    const short* __restrict__ w1p, const short* __restrict__ w2p,
    const float* __restrict__ b1, const float* __restrict__ b2,
    const float* __restrict__ x, float* __restrict__ out)
{
    __shared__ __align__(16) char smem[65536];
    short* Ash = (short*)smem;               // [64][256] bf16 swizzled
    short* Hsh = (short*)(smem + 32768);     // [64][256] bf16 swizzled
    float* OT  = (float*)smem;               // [64][64] f32 swizzled (aliases Ash)

    const int tid  = threadIdx.x;
    const int lane = tid & 63;
    const int wid  = tid >> 6;
    const int M0 = blockIdx.x * 64;
    const int b = M0 >> 16, c = (M0 >> 8) & 255, h0 = M0 & 255;

    const int l15  = lane & 15;
    const int kg   = lane >> 4;   // 0..3

    // stage A tile (64 x 256 bf16), swizzle chunk16 ^= (row&7)
    {
        const uint4* src = reinterpret_cast<const uint4*>(ynorm + (size_t)M0*256);
        for (int i = tid; i < 2048; i += 256){
            int row = i >> 5, g = i & 31;
            uint4 v = src[i];
            *reinterpret_cast<uint4*>(Ash + row*256 + ((g ^ (row & 7)) << 3)) = v;
        }
    }
    __syncthreads();

    f32x4 acc2[4][4] = {};
    short8 pw1[4], pw2[4];

    // preload GEMM1 ks=0 fragments for oc=0
    #pragma unroll
    for (int nfi = 0; nfi < 4; ++nfi)
        pw1[nfi] = *reinterpret_cast<const short8*>(
            w1p + ((size_t)(((0*16 + wid*4 + nfi)*8 + 0)*64 + lane)) * 8);

    #pragma unroll
    for (int oc = 0; oc < 4; ++oc){
        f32x4 acc1[4][4] = {};
        // ---- GEMM1: h-chunk = A(64x256) @ W1-slice(256x256)
        #pragma unroll
        for (int ks = 0; ks < 8; ++ks){
            short8 afr[4], bfr[4];
            #pragma unroll
            for (int mf = 0; mf < 4; ++mf){
                int row = mf*16 + l15;
                afr[mf] = *reinterpret_cast<const short8*>(
                    Ash + row*256 + (((ks*4 + kg) ^ (l15 & 7)) << 3));
            }
            if (ks == 0){
                #pragma unroll
                for (int nfi = 0; nfi < 4; ++nfi) bfr[nfi] = pw1[nfi];
            } else {
                #pragma unroll
                for (int nfi = 0; nfi < 4; ++nfi)
                    bfr[nfi] = *reinterpret_cast<const short8*>(
                        w1p + ((size_t)(((oc*16 + wid*4 + nfi)*8 + ks)*64 + lane)) * 8);
            }
            #pragma unroll
            for (int mf = 0; mf < 4; ++mf){
                #pragma unroll
                for (int nfi = 0; nfi < 4; ++nfi)
                    acc1[mf][nfi] = mfma16(afr[mf], bfr[nfi], acc1[mf][nfi]);
            }
        }

        // prefetch across the barriers: GEMM2 ks=0 frags (this oc) and
        // GEMM1 ks=0 frags (next oc)
        #pragma unroll
        for (int nfi = 0; nfi < 4; ++nfi)
            pw2[nfi] = *reinterpret_cast<const short8*>(
                w2p + ((size_t)(((nfi*4 + wid)*32 + oc*8 + 0)*64 + lane)) * 8);
        if (oc < 3){
            #pragma unroll
            for (int nfi = 0; nfi < 4; ++nfi)
                pw1[nfi] = *reinterpret_cast<const short8*>(
                    w1p + ((size_t)((((oc+1)*16 + wid*4 + nfi)*8 + 0)*64 + lane)) * 8);
        }

        __syncthreads();   // prev GEMM2 readers of Hsh done
        // ---- bias + fast GELU -> Hsh (bf16, swizzled)
        #pragma unroll
        for (int nfi = 0; nfi < 4; ++nfi){
            int col = (wid*4 + nfi)*16 + l15;
            float bb = b1[oc*256 + col];
            #pragma unroll
            for (int mf = 0; mf < 4; ++mf){
                #pragma unroll
                for (int r = 0; r < 4; ++r){
                    int row = mf*16 + kg*4 + r;
                    float v = acc1[mf][nfi][r] + bb;
                    float g = gelu_fast(v);
                    Hsh[row*256 + (((col >> 3) ^ (row & 7)) << 3) + (col & 7)] = (short)bf16of(g);
                }
            }
        }
        __syncthreads();
        // ---- GEMM2 partial: out += H-chunk(64x256) @ W2-slice(256x256)
        #pragma unroll
        for (int ks = 0; ks < 8; ++ks){
            short8 hfr[4], bfr[4];
            #pragma unroll
            for (int mf = 0; mf < 4; ++mf){
                int row = mf*16 + l15;
                hfr[mf] = *reinterpret_cast<const short8*>(
                    Hsh + row*256 + (((ks*4 + kg) ^ (l15 & 7)) << 3));
            }
            if (ks == 0){
                #pragma unroll
                for (int nfi = 0; nfi < 4; ++nfi) bfr[nfi] = pw2[nfi];
            } else {
                #pragma unroll
                for (int nfi = 0; nfi < 4; ++nfi)
                    bfr[nfi] = *reinterpret_cast<const short8*>(
                        w2p + ((size_t)(((nfi*4 + wid)*32 + oc*8 + ks)*64 + lane)) * 8);
            }
            #pragma unroll
            for (int mf = 0; mf < 4; ++mf){
                #pragma unroll
                for (int nfi = 0; nfi < 4; ++nfi)
                    acc2[mf][nfi] = mfma16(hfr[mf], bfr[nfi], acc2[mf][nfi]);
            }
        }
    }

    // epilogue: 4 rounds; round r transposes w-range [r*64, r*64+64)
    // GEMM2 N mapping (wcol = nfi*64 + wid*16 + l15): all 4 waves hold nfi==r data.
    #pragma unroll
    for (int r = 0; r < 4; ++r){
        __syncthreads();
        int wl = wid*16 + l15;
        #pragma unroll
        for (int mf = 0; mf < 4; ++mf){
            #pragma unroll
            for (int j = 0; j < 4; ++j){
                int h = mf*16 + kg*4 + j;
                OT[wl*64 + (((h >> 2) ^ (wl & 15)) << 2) + (h & 3)] = acc2[mf][r][j];
            }
        }
        __syncthreads();
        #pragma unroll
        for (int it = 0; it < 4; ++it){
            int idx = it*256 + tid;
            int wl2 = idx >> 4, h4 = idx & 15;
            int wg = r*64 + wl2;
            float bb = b2[wg];
            size_t o = (((size_t)(b*256 + wg))*256 + (size_t)c)*256 + (size_t)(h0 + h4*4);
            float4 xa = *reinterpret_cast<const float4*>(x + o);
            int base = wl2*64 + ((h4 ^ (wl2 & 15)) << 2);
            float4 rv;
            rv.x = OT[base + 0] + bb + xa.x;
            rv.y = OT[base + 1] + bb + xa.y;
            rv.z = OT[base + 2] + bb + xa.z;
            rv.w = OT[base + 3] + bb + xa.w;
            *reinterpret_cast<float4*>(out + o) = rv;
        }
    }
}

// ---------------------------------------------------------------- launch
extern "C" void kernel_launch(void* const* d_in, const int* in_sizes, int n_in,
                              void* d_out, int out_size, void* d_ws, size_t ws_size,
                              hipStream_t stream)
{
    const float* x      = (const float*)d_in[0];
    const float* conv_w = (const float*)d_in[1];
    const float* conv_b = (const float*)d_in[2];
    const float* ln_g   = (const float*)d_in[3];
    const float* ln_b   = (const float*)d_in[4];
    const float* w1     = (const float*)d_in[5];
    const float* b1     = (const float*)d_in[6];
    const float* w2     = (const float*)d_in[7];
    const float* b2     = (const float*)d_in[8];
    float* out = (float*)d_out;

    unsigned short* ynorm = (unsigned short*)d_ws;                          // 67,108,864 B
    unsigned short* w1p   = (unsigned short*)((char*)d_ws + 67108864);      //    524,288 B
    unsigned short* w2p   = (unsigned short*)((char*)d_ws + 67108864 + 524288);

    hipLaunchKernelGGL(prep_weights, dim3(256), dim3(256), 0, stream, w1, w2, w1p, w2p);
    hipLaunchKernelGGL(conv_ln_kernel, dim3(8192), dim3(256), 0, stream,
                       x, conv_w, conv_b, ln_g, ln_b, ynorm);
    hipLaunchKernelGGL(mlp_kernel, dim3(2048), dim3(256), 0, stream,
                       ynorm, (const short*)w1p, (const short*)w2p, b1, b2, x, out);
}

// Round 4
// 400.437 us; speedup vs baseline: 1.3925x; 1.0375x over previous
//
#include <hip/hip_runtime.h>
#include <hip/hip_bf16.h>
#include <math.h>

using short8 = __attribute__((ext_vector_type(8))) short;
using f32x4  = __attribute__((ext_vector_type(4))) float;

static __device__ __forceinline__ f32x4 mfma16(short8 a, short8 b, f32x4 c){
    return __builtin_amdgcn_mfma_f32_16x16x32_bf16(a, b, c, 0, 0, 0);
}

// round-to-nearest-even f32 -> bf16 bits (finite values only)
static __device__ __forceinline__ unsigned short bf16of(float f){
    unsigned int u = __float_as_uint(f);
    unsigned int lsb = (u >> 16) & 1u;
    u += 0x7fffu + lsb;
    return (unsigned short)(u >> 16);
}

// fast GELU (tanh form): max abs err ~3e-4, far under tolerance
static __device__ __forceinline__ float gelu_fast(float x){
    float x2 = x * x;
    float u2 = 1.5957691216057308f * x * fmaf(0.044715f, x2, 1.0f);
    float e  = __expf(-u2);
    return x * __builtin_amdgcn_rcpf(1.0f + e);
}

// ---------------------------------------------------------------- prep
// Pack w1/w2 into MFMA-fragment-major bf16 layouts (operand layout identical
// for A- and B-side: lane&15 -> outer index, (lane>>4)*8+j -> k):
// w1p[(n16*8 + ks)*64 + lane][8]: o = n16*16 + (lane&15), k = ks*32 + (lane>>4)*8 + j
// w2p[(n16*32 + ksg)*64 + lane][8]: w = n16*16 + (lane&15), o = ksg*32 + (lane>>4)*8 + j
__global__ __launch_bounds__(256) void prep_weights(
    const float* __restrict__ w1, const float* __restrict__ w2,
    unsigned short* __restrict__ w1p, unsigned short* __restrict__ w2p)
{
    int t = blockIdx.x * 256 + threadIdx.x;   // 0..65535
    int lane = t & 63;
    if (t < 32768){
        int g = t;
        int ks  = (g >> 6) & 7;
        int n16 = g >> 9;
        int o = n16*16 + (lane & 15);
        int k = ks*32 + (lane >> 4)*8;
        const float* src = w1 + o*256 + k;
        unsigned short* dst = w1p + (size_t)g*8;
        #pragma unroll
        for (int j = 0; j < 8; ++j) dst[j] = bf16of(src[j]);
    } else {
        int g = t - 32768;
        int ksg = (g >> 6) & 31;
        int n16 = g >> 11;
        int n = n16*16 + (lane & 15);
        int k = ksg*32 + (lane >> 4)*8;
        const float* src = w2 + n*1024 + k;
        unsigned short* dst = w2p + (size_t)g*8;
        #pragma unroll
        for (int j = 0; j < 8; ++j) dst[j] = bf16of(src[j]);
    }
}

// ---------------------------------------------------------------- conv + LN
#define CH 16          // output h-rows per block
#define XR (CH + 6)    // input rows incl. halo
#define XW 262         // tile width incl. halo

__global__ __launch_bounds__(256) void conv_ln_kernel(
    const float* __restrict__ x, const float* __restrict__ conv_w,
    const float* __restrict__ conv_b, const float* __restrict__ ln_g,
    const float* __restrict__ ln_b, unsigned short* __restrict__ ynorm)
{
    __shared__ float xt[XR * XW];
    __shared__ float yt[CH * 256];

    const int tid = threadIdx.x;
    const int blk = blockIdx.x;
    const int ht = blk & 15;
    const int c  = (blk >> 4) & 255;
    const int b  = blk >> 12;
    const int h0 = ht * CH;

    const float* xplane = x + (((size_t)(b*256 + c)) << 16);

    for (int i = tid; i < XR*XW; i += 256){
        int r = i / XW;
        int col = i - r*XW;
        int gh = h0 - 3 + r;
        int gw = col - 3;
        float v = 0.f;
        if ((unsigned)gh < 256u && (unsigned)gw < 256u)
            v = xplane[gh*256 + gw];
        xt[i] = v;
    }

    float cwr[49];
    #pragma unroll
    for (int i = 0; i < 49; ++i) cwr[i] = conv_w[c*49 + i];
    const float cb = conv_b[c];

    __syncthreads();

    const int w = tid;
    float acc[CH];
    #pragma unroll
    for (int r = 0; r < CH; ++r) acc[r] = 0.f;

    #pragma unroll
    for (int i = 0; i < XR; ++i){
        #pragma unroll
        for (int j = 0; j < 7; ++j){
            float v = xt[i*XW + w + j];
            #pragma unroll
            for (int ro = 0; ro < CH; ++ro){
                if (ro >= i - 6 && ro <= i)
                    acc[ro] = fmaf(v, cwr[(i - ro)*7 + j], acc[ro]);
            }
        }
    }

    #pragma unroll
    for (int r = 0; r < CH; ++r) yt[r*256 + w] = acc[r] + cb;

    __syncthreads();

    const int lane = tid & 63;
    const int wid  = tid >> 6;
    float lg[4], lb[4];
    #pragma unroll
    for (int q = 0; q < 4; ++q){ lg[q] = ln_g[lane + 64*q]; lb[q] = ln_b[lane + 64*q]; }

    for (int rr = 0; rr < CH/4; ++rr){
        int row = wid*(CH/4) + rr;
        float v[4], s = 0.f, ss = 0.f;
        #pragma unroll
        for (int q = 0; q < 4; ++q){
            v[q] = yt[row*256 + lane + 64*q];
            s += v[q]; ss += v[q]*v[q];
        }
        #pragma unroll
        for (int off = 32; off > 0; off >>= 1){
            s  += __shfl_xor(s, off);
            ss += __shfl_xor(ss, off);
        }
        float mu  = s * (1.f/256.f);
        float var = ss * (1.f/256.f) - mu*mu;
        float rs  = rsqrtf(var + 1e-5f);
        size_t M = (size_t)((b*256 + c)*256 + h0 + row);
        unsigned short* dst = ynorm + M*256;
        #pragma unroll
        for (int q = 0; q < 4; ++q){
            float o = (v[q] - mu)*rs*lg[q] + lb[q];
            dst[lane + 64*q] = bf16of(o);
        }
    }
}

// ---------------------------------------------------------------- fused MLP + transposed-out residual
// 4 waves, M-tile 64, waves split N. N-chunk 256 (oc=0..3) -> 8 barriers total.
// GEMM1: acc1 = P[m][o] via mfma(Y, W1).  GEMM2 SWAPPED: mfma(W2, H) computes
// Out2^T[w][m] directly -> epilogue is barrier-free 64B-coalesced stores fused
// with the x residual; the OT transpose buffer and its 8 barriers are gone.
__global__ __launch_bounds__(256, 2) void mlp_kernel(
    const unsigned short* __restrict__ ynorm,
    const short* __restrict__ w1p, const short* __restrict__ w2p,
    const float* __restrict__ b1, const float* __restrict__ b2,
    const float* __restrict__ x, float* __restrict__ out)
{
    __shared__ __align__(16) char smem[65536];
    short* Ash = (short*)smem;               // [64][256] bf16 swizzled
    short* Hsh = (short*)(smem + 32768);     // [64][256] bf16 swizzled

    const int tid  = threadIdx.x;
    const int lane = tid & 63;
    const int wid  = tid >> 6;
    const int M0 = blockIdx.x * 64;
    const int b = M0 >> 16, c = (M0 >> 8) & 255, h0 = M0 & 255;

    const int l15  = lane & 15;
    const int kg   = lane >> 4;   // 0..3

    // stage A tile (64 x 256 bf16), swizzle chunk16 ^= (row&7)
    {
        const uint4* src = reinterpret_cast<const uint4*>(ynorm + (size_t)M0*256);
        for (int i = tid; i < 2048; i += 256){
            int row = i >> 5, g = i & 31;
            uint4 v = src[i];
            *reinterpret_cast<uint4*>(Ash + row*256 + ((g ^ (row & 7)) << 3)) = v;
        }
    }
    __syncthreads();

    f32x4 acc2[4][4] = {};
    short8 pw1[4], pw2[4];

    // preload GEMM1 ks=0 fragments for oc=0
    #pragma unroll
    for (int nfi = 0; nfi < 4; ++nfi)
        pw1[nfi] = *reinterpret_cast<const short8*>(
            w1p + ((size_t)(((0*16 + wid*4 + nfi)*8 + 0)*64 + lane)) * 8);

    #pragma unroll
    for (int oc = 0; oc < 4; ++oc){
        f32x4 acc1[4][4] = {};
        // ---- GEMM1: P-chunk = Y(64x256) @ W1-slice(256x256)^T
        #pragma unroll
        for (int ks = 0; ks < 8; ++ks){
            short8 afr[4], bfr[4];
            #pragma unroll
            for (int mf = 0; mf < 4; ++mf){
                int row = mf*16 + l15;
                afr[mf] = *reinterpret_cast<const short8*>(
                    Ash + row*256 + (((ks*4 + kg) ^ (l15 & 7)) << 3));
            }
            if (ks == 0){
                #pragma unroll
                for (int nfi = 0; nfi < 4; ++nfi) bfr[nfi] = pw1[nfi];
            } else {
                #pragma unroll
                for (int nfi = 0; nfi < 4; ++nfi)
                    bfr[nfi] = *reinterpret_cast<const short8*>(
                        w1p + ((size_t)(((oc*16 + wid*4 + nfi)*8 + ks)*64 + lane)) * 8);
            }
            #pragma unroll
            for (int mf = 0; mf < 4; ++mf){
                #pragma unroll
                for (int nfi = 0; nfi < 4; ++nfi)
                    acc1[mf][nfi] = mfma16(afr[mf], bfr[nfi], acc1[mf][nfi]);
            }
        }

        // prefetch across the barriers: GEMM2 ks=0 frags (this oc) and
        // GEMM1 ks=0 frags (next oc)
        #pragma unroll
        for (int nfi = 0; nfi < 4; ++nfi)
            pw2[nfi] = *reinterpret_cast<const short8*>(
                w2p + ((size_t)(((wid*4 + nfi)*32 + oc*8 + 0)*64 + lane)) * 8);
        if (oc < 3){
            #pragma unroll
            for (int nfi = 0; nfi < 4; ++nfi)
                pw1[nfi] = *reinterpret_cast<const short8*>(
                    w1p + ((size_t)((((oc+1)*16 + wid*4 + nfi)*8 + 0)*64 + lane)) * 8);
        }

        __syncthreads();   // prev GEMM2 readers of Hsh done
        // ---- bias + fast GELU -> Hsh (bf16, swizzled)
        // acc1[mf][nfi][r] = P[m = mf*16+kg*4+r][o = (wid*4+nfi)*16 + l15]
        #pragma unroll
        for (int nfi = 0; nfi < 4; ++nfi){
            int col = (wid*4 + nfi)*16 + l15;
            float bb = b1[oc*256 + col];
            #pragma unroll
            for (int mf = 0; mf < 4; ++mf){
                #pragma unroll
                for (int r = 0; r < 4; ++r){
                    int row = mf*16 + kg*4 + r;
                    float v = acc1[mf][nfi][r] + bb;
                    float g = gelu_fast(v);
                    Hsh[row*256 + (((col >> 3) ^ (row & 7)) << 3) + (col & 7)] = (short)bf16of(g);
                }
            }
        }
        __syncthreads();
        // ---- GEMM2 partial (SWAPPED): Out2^T[w][m] += W2-slice @ H-chunk^T
        #pragma unroll
        for (int ks = 0; ks < 8; ++ks){
            short8 hfr[4], wfr[4];
            #pragma unroll
            for (int mf = 0; mf < 4; ++mf){
                int row = mf*16 + l15;
                hfr[mf] = *reinterpret_cast<const short8*>(
                    Hsh + row*256 + (((ks*4 + kg) ^ (l15 & 7)) << 3));
            }
            if (ks == 0){
                #pragma unroll
                for (int nfi = 0; nfi < 4; ++nfi) wfr[nfi] = pw2[nfi];
            } else {
                #pragma unroll
                for (int nfi = 0; nfi < 4; ++nfi)
                    wfr[nfi] = *reinterpret_cast<const short8*>(
                        w2p + ((size_t)(((wid*4 + nfi)*32 + oc*8 + ks)*64 + lane)) * 8);
            }
            #pragma unroll
            for (int mf = 0; mf < 4; ++mf){
                #pragma unroll
                for (int nfi = 0; nfi < 4; ++nfi)
                    acc2[mf][nfi] = mfma16(wfr[nfi], hfr[mf], acc2[mf][nfi]);
            }
        }
    }

    // ---- barrier-free epilogue:
    // acc2[mf][nfi][r] = Out2^T[w = (wid*4+nfi)*16 + kg*4 + r][m = mf*16 + l15]
    // out[b][w][c][h0+m] = acc2 + b2[w] + x[...]; quarter-wave -> 64B runs.
    #pragma unroll
    for (int nfi = 0; nfi < 4; ++nfi){
        #pragma unroll
        for (int r = 0; r < 4; ++r){
            int w = (wid*4 + nfi)*16 + kg*4 + r;
            float bb = b2[w];
            size_t base = ((size_t)b << 24) + ((size_t)w << 16) + (c << 8) + h0 + l15;
            #pragma unroll
            for (int mf = 0; mf < 4; ++mf){
                size_t o = base + mf*16;
                out[o] = acc2[mf][nfi][r] + bb + x[o];
            }
        }
    }
}

// ---------------------------------------------------------------- launch
extern "C" void kernel_launch(void* const* d_in, const int* in_sizes, int n_in,
                              void* d_out, int out_size, void* d_ws, size_t ws_size,
                              hipStream_t stream)
{
    const float* x      = (const float*)d_in[0];
    const float* conv_w = (const float*)d_in[1];
    const float* conv_b = (const float*)d_in[2];
    const float* ln_g   = (const float*)d_in[3];
    const float* ln_b   = (const float*)d_in[4];
    const float* w1     = (const float*)d_in[5];
    const float* b1     = (const float*)d_in[6];
    const float* w2     = (const float*)d_in[7];
    const float* b2     = (const float*)d_in[8];
    float* out = (float*)d_out;

    unsigned short* ynorm = (unsigned short*)d_ws;                          // 67,108,864 B
    unsigned short* w1p   = (unsigned short*)((char*)d_ws + 67108864);      //    524,288 B
    unsigned short* w2p   = (unsigned short*)((char*)d_ws + 67108864 + 524288);

    hipLaunchKernelGGL(prep_weights, dim3(256), dim3(256), 0, stream, w1, w2, w1p, w2p);
    hipLaunchKernelGGL(conv_ln_kernel, dim3(8192), dim3(256), 0, stream,
                       x, conv_w, conv_b, ln_g, ln_b, ynorm);
    hipLaunchKernelGGL(mlp_kernel, dim3(2048), dim3(256), 0, stream,
                       ynorm, (const short*)w1p, (const short*)w2p, b1, b2, x, out);
}